// Round 5
// baseline (621.726 us; speedup 1.0000x reference)
//
#include <hip/hip_runtime.h>

// Resample2d (Flownet2-style) bilinear warp.
// feature: [B,C,H,W] fp32, flow: [B,2,H,W] fp32, out: [B,C,H,W] fp32.
//
// R6: TLP + amortization together. R4 (32 waves/CU, no pipeline) == R5
// (16 waves/CU, pipeline) at ~57k cyc per 8ch-tile with every pipe <30%
// busy -> latency-stall bound; each structure was missing the other's
// lever. Changes vs R5:
//  - Single 64,064B LDS buffer (fits 2 blocks/CU -> 32 waves/CU). Per
//    group: STAGE_LOAD(g+1) -> COMPUTE(g) -> barrier -> STAGE_WRITE ->
//    barrier. Cross-block overlap covers the write/barrier bubble.
//  - __launch_bounds__(1024,8) to force VGPR<=64 (8 waves/SIMD). Register
//    diet: vmask -> bitmask, sOff/pixk recomputed, not stored.
//  - Keep: GPB=4 (8ch) amortization, CPB=2 float2 sites, odd SW=91,
//    hoisted flow/weights, rare global fallback, nontemporal stores,
//    bijective XCD swizzle.

#define Bv 2
#define Cv 64
#define Hv 512
#define Wv 896
#define HWsz (Hv * Wv)

#define TILE 64
#define CPB 2                    // channels per LDS site (float2)
#define GPB 4                    // channel-groups per block -> 8 channels
#define NCG (Cv / CPB)           // 32
#define NCGB (NCG / GPB)         // 8 group-batches
#define SW 91                    // staged cols; ODD -> bank mixing
#define SH 88                    // staged rows
#define XOFF 12
#define YOFF 11
#define NSITES (SH * SW)         // 8008
#define NTX (Wv / TILE)          // 14
#define NTY (Hv / TILE)          // 8
#define NTILES (NTX * NTY)       // 112
#define NBLK (Bv * NCGB * NTILES)  // 1792 = 7*256, %8==0
#define THREADS 1024
#define NW (THREADS / 64)        // 16 waves
#define KITERS (TILE * TILE / THREADS)      // 4 pixel-iters/thread
#define SITE_ITERS ((NSITES + THREADS - 1) / THREADS)  // 8

__global__ __launch_bounds__(THREADS, 8) void resample2d_kernel(
    const float* __restrict__ feature,
    const float* __restrict__ flow,
    float* __restrict__ out) {
    __shared__ float2 smem[NSITES];  // 64,064 B -> 2 blocks/CU

    // Bijective XCD-chunked swizzle (NBLK % 8 == 0): consecutive wids are
    // adjacent tiles of the same channel planes -> halo re-reads are L2 hits.
    const int orig = blockIdx.x;
    const int wid = (orig & 7) * (NBLK / 8) + (orig >> 3);
    const int txi = wid % NTX;
    const int t2 = wid / NTX;
    const int tyi = t2 % NTY;
    const int zb = t2 / NTY;        // (b, group-batch)
    const int b = zb / NCGB;
    const int c0 = (zb % NCGB) * (GPB * CPB);

    const int tx0 = txi * TILE;
    const int ty0 = tyi * TILE;
    const int xs = tx0 - XOFF;
    const int ys = ty0 - YOFF;

    const int tid = threadIdx.x;
    const int lane = tid & 63;
    const int wv = tid >> 6;

    const float* __restrict__ fbase = feature + ((size_t)b * Cv + c0) * HWsz;
    const float* __restrict__ flb = flow + (size_t)b * 2 * HWsz;
    float* __restrict__ ob = out + ((size_t)b * Cv + c0) * HWsz;

    // ---- A: flow loads (latency hides under site precompute below)
    const int px = tx0 + lane;
    float u[KITERS], v[KITERS];
#pragma unroll
    for (int k = 0; k < KITERS; ++k) {
        const int pix = (ty0 + wv + NW * k) * Wv + px;
        u[k] = flb[pix];
        v[k] = flb[HWsz + pix];
    }

    // ---- Per-thread staging-site precompute (ONCE; reused for all groups).
    // Lanes with p >= NSITES clamp to the last site (duplicate identical
    // writes, benign). Validity packed into a bitmask (register diet).
    int gOff[SITE_ITERS];
    unsigned vbits = 0;
#pragma unroll
    for (int i = 0; i < SITE_ITERS; ++i) {
        const int p = tid + THREADS * i;
        const int pc = (p < NSITES) ? p : (NSITES - 1);
        const int r = pc / SW;
        const int xx = pc - r * SW;
        const int gy = ys + r;
        const int gx = xs + xx;
        const bool vd = ((unsigned)gy < (unsigned)Hv) & ((unsigned)gx < (unsigned)Wv);
        gOff[i] = vd ? (gy * Wv + gx) : 0;
        vbits |= vd ? (1u << i) : 0u;
    }

#define STAGE_LOAD(G)                                            \
    do {                                                         \
        const float* __restrict__ fg_ =                          \
            fbase + (size_t)(G) * CPB * HWsz;                    \
        _Pragma("unroll") for (int i = 0; i < SITE_ITERS; ++i) { \
            a0[i] = fg_[gOff[i]];                                \
            a1[i] = fg_[gOff[i] + HWsz];                         \
        }                                                        \
    } while (0)

#define STAGE_WRITE()                                                       \
    do {                                                                    \
        _Pragma("unroll") for (int i = 0; i < SITE_ITERS; ++i) {            \
            const int p_ = tid + THREADS * i;                               \
            const int pc_ = (p_ < NSITES) ? p_ : (NSITES - 1);              \
            const float m_ = (vbits & (1u << i)) ? 1.0f : 0.0f;             \
            smem[pc_] = make_float2(a0[i] * m_, a1[i] * m_);                \
        }                                                                   \
    } while (0)

    float a0[SITE_ITERS], a1[SITE_ITERS];
    STAGE_LOAD(0);

    // ---- C: weights + clamped LDS site addresses (ONCE; no LDS dep; VALU
    // overlaps the in-flight stage loads). Reused by all GPB groups.
    float w00k[KITERS], w10k[KITERS], w01k[KITERS], w11k[KITERS];
    int ac[KITERS];
    unsigned iw = 0;
#pragma unroll
    for (int k = 0; k < KITERS; ++k) {
        const int y = ty0 + wv + NW * k;
        const float gx = u[k] + (float)px;
        const float gy = v[k] + (float)y;
        const float x0f = floorf(gx);
        const float y0f = floorf(gy);
        const float wx = gx - x0f;
        const float wy = gy - y0f;
        const float omx = 1.0f - wx;
        const float omy = 1.0f - wy;
        w00k[k] = omx * omy;
        w10k[k] = wx * omy;
        w01k[k] = omx * wy;
        w11k[k] = wx * wy;
        const int lx = (int)x0f - xs;
        const int ly = (int)y0f - ys;
        const bool inwin = ((unsigned)lx <= (unsigned)(SW - 2)) &
                           ((unsigned)ly <= (unsigned)(SH - 2));
        iw |= inwin ? (1u << k) : 0u;
        const int lxc = min(max(lx, 0), SW - 2);
        const int lyc = min(max(ly, 0), SH - 2);
        ac[k] = lyc * SW + lxc;
    }

#define COMPUTE(G)                                                             \
    do {                                                                       \
        float* __restrict__ og_ = ob + (size_t)(G) * CPB * HWsz;               \
        const float* __restrict__ fg_ = fbase + (size_t)(G) * CPB * HWsz;      \
        _Pragma("unroll") for (int k = 0; k < KITERS; ++k) {                   \
            float2 t00 = smem[ac[k]];                                          \
            float2 t10 = smem[ac[k] + 1];                                      \
            float2 t01 = smem[ac[k] + SW];                                     \
            float2 t11 = smem[ac[k] + SW + 1];                                 \
            if (!(iw & (1u << k))) { /* rare Gaussian-tail fallback */         \
                const int y_ = ty0 + wv + NW * k;                              \
                const float gx_ = u[k] + (float)px;                            \
                const float gy_ = v[k] + (float)y_;                            \
                const int x0_ = (int)floorf(gx_);                              \
                const int y0_ = (int)floorf(gy_);                              \
                const int x1_ = x0_ + 1, y1_ = y0_ + 1;                        \
                const bool vx0 = (unsigned)x0_ < (unsigned)Wv;                 \
                const bool vx1 = (unsigned)x1_ < (unsigned)Wv;                 \
                const bool vy0 = (unsigned)y0_ < (unsigned)Hv;                 \
                const bool vy1 = (unsigned)y1_ < (unsigned)Hv;                 \
                const int cx0 = min(max(x0_, 0), Wv - 1);                      \
                const int cx1 = min(max(x1_, 0), Wv - 1);                      \
                const int cy0 = min(max(y0_, 0), Hv - 1);                      \
                const int cy1 = min(max(y1_, 0), Hv - 1);                      \
                _Pragma("unroll") for (int c = 0; c < CPB; ++c) {              \
                    const float* f = fg_ + (size_t)c * HWsz;                   \
                    ((float*)&t00)[c] = (vx0 & vy0) ? f[cy0 * Wv + cx0] : 0.f; \
                    ((float*)&t10)[c] = (vx1 & vy0) ? f[cy0 * Wv + cx1] : 0.f; \
                    ((float*)&t01)[c] = (vx0 & vy1) ? f[cy1 * Wv + cx0] : 0.f; \
                    ((float*)&t11)[c] = (vx1 & vy1) ? f[cy1 * Wv + cx1] : 0.f; \
                }                                                              \
            }                                                                  \
            const float r0 = t00.x * w00k[k] + t10.x * w10k[k] +               \
                             t01.x * w01k[k] + t11.x * w11k[k];                \
            const float r1 = t00.y * w00k[k] + t10.y * w10k[k] +               \
                             t01.y * w01k[k] + t11.y * w11k[k];                \
            const int pix_ = (ty0 + wv + NW * k) * Wv + px;                    \
            __builtin_nontemporal_store(r0, &og_[pix_]);                       \
            __builtin_nontemporal_store(r1, &og_[HWsz + pix_]);                \
        }                                                                      \
    } while (0)

    // ---- Pipelined group loop, single buffer, two barriers per group:
    //   STAGE_LOAD(g+1) ; COMPUTE(g) ; barrier ; STAGE_WRITE ; barrier
    // Stage-load latency hides under COMPUTE; co-resident block covers the
    // write/barrier bubble.
    STAGE_WRITE();
    __syncthreads();

    STAGE_LOAD(1);
    COMPUTE(0);
    __syncthreads();
    STAGE_WRITE();
    __syncthreads();

    STAGE_LOAD(2);
    COMPUTE(1);
    __syncthreads();
    STAGE_WRITE();
    __syncthreads();

    STAGE_LOAD(3);
    COMPUTE(2);
    __syncthreads();
    STAGE_WRITE();
    __syncthreads();

    COMPUTE(3);

#undef STAGE_LOAD
#undef STAGE_WRITE
#undef COMPUTE
}

extern "C" void kernel_launch(void* const* d_in, const int* in_sizes, int n_in,
                              void* d_out, int out_size, void* d_ws, size_t ws_size,
                              hipStream_t stream) {
    const float* feature = (const float*)d_in[0];
    const float* flow = (const float*)d_in[1];
    float* out = (float*)d_out;

    dim3 block(THREADS, 1, 1);
    dim3 grid(NBLK, 1, 1);
    resample2d_kernel<<<grid, block, 0, stream>>>(feature, flow, out);
}

// Round 6
// 424.687 us; speedup vs baseline: 1.4640x; 1.4640x over previous
//
#include <hip/hip_runtime.h>

// Resample2d (Flownet2-style) bilinear warp.
// feature: [B,C,H,W] fp32, flow: [B,2,H,W] fp32, out: [B,C,H,W] fp32.
//
// R7: undo R6's spill disaster (launch_bounds(1024,8) capped VGPR at 32;
// the gOff/a0/a1 prefetch arrays spilled -> +463MB fetch +473MB write of
// scratch traffic). Keep the 2-blocks/CU goal but get registers down by
// REMOVING the register prefetch, not by forcing the allocator:
//  - R4-style lean staging: addresses recomputed inline, load->mask->
//    ds_write streamed, unroll 4 to bound live values. ~45 VGPR natural.
//  - Keep R5's GPB=4 amortization: flow loads, bilinear weights, gather
//    addresses computed ONCE per pixel for all 8 channels.
//  - Single 64,064B LDS buffer -> 2 blocks/CU (32 waves) co-resident; the
//    other block's COMPUTE covers this block's STAGE latency (R4 regime).
//  - Keep: CPB=2 float2 sites, odd SW=91, rare global fallback,
//    nontemporal stores, bijective XCD swizzle, grid=1792 (7 blocks/CU).

#define Bv 2
#define Cv 64
#define Hv 512
#define Wv 896
#define HWsz (Hv * Wv)

#define TILE 64
#define CPB 2                    // channels per LDS site (float2)
#define GPB 4                    // channel-groups per block -> 8 channels
#define NCG (Cv / CPB)           // 32
#define NCGB (NCG / GPB)         // 8 group-batches
#define SW 91                    // staged cols; ODD -> bank mixing
#define SH 88                    // staged rows
#define XOFF 12
#define YOFF 11
#define NSITES (SH * SW)         // 8008
#define NTX (Wv / TILE)          // 14
#define NTY (Hv / TILE)          // 8
#define NTILES (NTX * NTY)       // 112
#define NBLK (Bv * NCGB * NTILES)  // 1792 = 7*256, %8==0
#define THREADS 1024
#define NW (THREADS / 64)        // 16 waves
#define KITERS (TILE * TILE / THREADS)      // 4 pixel-iters/thread
#define SITE_ITERS ((NSITES + THREADS - 1) / THREADS)  // 8

__global__ __launch_bounds__(THREADS) void resample2d_kernel(
    const float* __restrict__ feature,
    const float* __restrict__ flow,
    float* __restrict__ out) {
    __shared__ float2 smem[NSITES];  // 64,064 B -> 2 blocks/CU

    // Bijective XCD-chunked swizzle (NBLK % 8 == 0): consecutive wids are
    // adjacent tiles of the same channel planes -> halo re-reads are L2 hits.
    const int orig = blockIdx.x;
    const int wid = (orig & 7) * (NBLK / 8) + (orig >> 3);
    const int txi = wid % NTX;
    const int t2 = wid / NTX;
    const int tyi = t2 % NTY;
    const int zb = t2 / NTY;        // (b, group-batch)
    const int b = zb / NCGB;
    const int c0 = (zb % NCGB) * (GPB * CPB);

    const int tx0 = txi * TILE;
    const int ty0 = tyi * TILE;
    const int xs = tx0 - XOFF;
    const int ys = ty0 - YOFF;

    const int tid = threadIdx.x;
    const int lane = tid & 63;
    const int wv = tid >> 6;

    const float* __restrict__ fbase = feature + ((size_t)b * Cv + c0) * HWsz;
    const float* __restrict__ flb = flow + (size_t)b * 2 * HWsz;
    float* __restrict__ ob = out + ((size_t)b * Cv + c0) * HWsz;

    // ---- A: flow loads (issued first; latency hides under weight math)
    const int px = tx0 + lane;
    float u[KITERS], v[KITERS];
#pragma unroll
    for (int k = 0; k < KITERS; ++k) {
        const int pix = (ty0 + wv + NW * k) * Wv + px;
        u[k] = flb[pix];
        v[k] = flb[HWsz + pix];
    }

    // ---- C: weights + clamped LDS site addresses (ONCE; reused by all
    // GPB groups). iw = in-window bitmask.
    float w00k[KITERS], w10k[KITERS], w01k[KITERS], w11k[KITERS];
    int ac[KITERS];
    unsigned iw = 0;
#pragma unroll
    for (int k = 0; k < KITERS; ++k) {
        const int y = ty0 + wv + NW * k;
        const float gx = u[k] + (float)px;
        const float gy = v[k] + (float)y;
        const float x0f = floorf(gx);
        const float y0f = floorf(gy);
        const float wx = gx - x0f;
        const float wy = gy - y0f;
        const float omx = 1.0f - wx;
        const float omy = 1.0f - wy;
        w00k[k] = omx * omy;
        w10k[k] = wx * omy;
        w01k[k] = omx * wy;
        w11k[k] = wx * wy;
        const int lx = (int)x0f - xs;
        const int ly = (int)y0f - ys;
        const bool inwin = ((unsigned)lx <= (unsigned)(SW - 2)) &
                           ((unsigned)ly <= (unsigned)(SH - 2));
        iw |= inwin ? (1u << k) : 0u;
        const int lxc = min(max(lx, 0), SW - 2);
        const int lyc = min(max(ly, 0), SH - 2);
        ac[k] = lyc * SW + lxc;
    }

    // Lean staging: addresses recomputed inline each group (VALU is cheap,
    // registers are the scarce resource). unroll 4 bounds live loads.
#define STAGE(G)                                                              \
    do {                                                                      \
        const float* __restrict__ fg_ = fbase + (size_t)(G) * CPB * HWsz;     \
        _Pragma("unroll 4") for (int i = 0; i < SITE_ITERS; ++i) {            \
            const int p_ = tid + THREADS * i;                                 \
            const int pc_ = (p_ < NSITES) ? p_ : (NSITES - 1);                \
            const int r_ = pc_ / SW;                                          \
            const int xx_ = pc_ - r_ * SW;                                    \
            const int gy_ = ys + r_;                                          \
            const int gx_ = xs + xx_;                                         \
            const bool vd_ = ((unsigned)gy_ < (unsigned)Hv) &                 \
                             ((unsigned)gx_ < (unsigned)Wv);                  \
            const int go_ = vd_ ? (gy_ * Wv + gx_) : 0;                       \
            const float m_ = vd_ ? 1.0f : 0.0f;                               \
            const float e0_ = fg_[go_];                                       \
            const float e1_ = fg_[go_ + HWsz];                                \
            smem[pc_] = make_float2(e0_ * m_, e1_ * m_);                      \
        }                                                                     \
    } while (0)

#define COMPUTE(G)                                                             \
    do {                                                                       \
        float* __restrict__ og_ = ob + (size_t)(G) * CPB * HWsz;               \
        const float* __restrict__ fg_ = fbase + (size_t)(G) * CPB * HWsz;      \
        _Pragma("unroll") for (int k = 0; k < KITERS; ++k) {                   \
            float2 t00 = smem[ac[k]];                                          \
            float2 t10 = smem[ac[k] + 1];                                      \
            float2 t01 = smem[ac[k] + SW];                                     \
            float2 t11 = smem[ac[k] + SW + 1];                                 \
            if (!(iw & (1u << k))) { /* rare Gaussian-tail fallback */         \
                const int y_ = ty0 + wv + NW * k;                              \
                const float gx_ = u[k] + (float)px;                            \
                const float gy_ = v[k] + (float)y_;                            \
                const int x0_ = (int)floorf(gx_);                              \
                const int y0_ = (int)floorf(gy_);                              \
                const int x1_ = x0_ + 1, y1_ = y0_ + 1;                        \
                const bool vx0 = (unsigned)x0_ < (unsigned)Wv;                 \
                const bool vx1 = (unsigned)x1_ < (unsigned)Wv;                 \
                const bool vy0 = (unsigned)y0_ < (unsigned)Hv;                 \
                const bool vy1 = (unsigned)y1_ < (unsigned)Hv;                 \
                const int cx0 = min(max(x0_, 0), Wv - 1);                      \
                const int cx1 = min(max(x1_, 0), Wv - 1);                      \
                const int cy0 = min(max(y0_, 0), Hv - 1);                      \
                const int cy1 = min(max(y1_, 0), Hv - 1);                      \
                _Pragma("unroll") for (int c = 0; c < CPB; ++c) {              \
                    const float* f = fg_ + (size_t)c * HWsz;                   \
                    ((float*)&t00)[c] = (vx0 & vy0) ? f[cy0 * Wv + cx0] : 0.f; \
                    ((float*)&t10)[c] = (vx1 & vy0) ? f[cy0 * Wv + cx1] : 0.f; \
                    ((float*)&t01)[c] = (vx0 & vy1) ? f[cy1 * Wv + cx0] : 0.f; \
                    ((float*)&t11)[c] = (vx1 & vy1) ? f[cy1 * Wv + cx1] : 0.f; \
                }                                                              \
            }                                                                  \
            const float r0 = t00.x * w00k[k] + t10.x * w10k[k] +               \
                             t01.x * w01k[k] + t11.x * w11k[k];                \
            const float r1 = t00.y * w00k[k] + t10.y * w10k[k] +               \
                             t01.y * w01k[k] + t11.y * w11k[k];                \
            const int pix_ = (ty0 + wv + NW * k) * Wv + px;                    \
            __builtin_nontemporal_store(r0, &og_[pix_]);                       \
            __builtin_nontemporal_store(r1, &og_[HWsz + pix_]);                \
        }                                                                      \
    } while (0)

    // ---- Group loop: STAGE(g); barrier; COMPUTE(g); barrier.
    // Co-resident block's COMPUTE overlaps this block's STAGE (2 blocks/CU).
    STAGE(0);
    __syncthreads();
    COMPUTE(0);
    __syncthreads();

    STAGE(1);
    __syncthreads();
    COMPUTE(1);
    __syncthreads();

    STAGE(2);
    __syncthreads();
    COMPUTE(2);
    __syncthreads();

    STAGE(3);
    __syncthreads();
    COMPUTE(3);

#undef STAGE
#undef COMPUTE
}

extern "C" void kernel_launch(void* const* d_in, const int* in_sizes, int n_in,
                              void* d_out, int out_size, void* d_ws, size_t ws_size,
                              hipStream_t stream) {
    const float* feature = (const float*)d_in[0];
    const float* flow = (const float*)d_in[1];
    float* out = (float*)d_out;

    dim3 block(THREADS, 1, 1);
    dim3 grid(NBLK, 1, 1);
    resample2d_kernel<<<grid, block, 0, stream>>>(feature, flow, out);
}